// Round 8
// baseline (254.536 us; speedup 1.0000x reference)
//
#include <hip/hip_runtime.h>

// GymNetwork: routed MLP, B=262144, D=128 -> F=80 -> 80 -> 80 -> A=18, G=8 (idx sorted).
// f32 I/O, bf16 MFMA compute (threshold 6e-2 = 8*bf16_eps*max|ref|).
//
// R4-R7: one-shot per-wave pipelines -> ~90% un-overlapped latency, all pipes idle.
// R8: each block loops over 4 tiles of 128 rows (512-row span), staging weights ONCE.
// Steady loop: prefetch next tile's state + g-range during current tile's compute;
// wave-private h buffers (no in-loop barriers); W4/biases in registers; W1 re-staged
// (barrier-pair) only on game change (<=1-2 per block; idx sorted).

#define B_TOT   262144
#define DDIM    128
#define FDIM    80
#define ADIM    18
#define ROWS_W  32     // rows per wave
#define MT      128    // rows per tile (4 waves)
#define SPAN    512    // rows per block
#define NITER   4      // SPAN/MT
#define SH      104    // LDS stride (shorts) for h rows

// swizzled bf16 weight workspace in d_ws (shorts); 512-short (1KB) chunks, lane-major
#define W1SW    0                       // 160 chunks: ((g*4+ks)*5+ct)
#define W2SW    81920                   // 15 chunks: (ks*5+ct), k pads zeroed
#define W3SW    89600                   // 15 chunks
#define W4SW    97280                   // 48 chunks: ((g*3+ks)*2+ct), n/k pads zeroed
#define WTOT    121856                  // shorts = 243712 bytes

// LDS layout (shorts)
#define LW1     0                       // 20 chunks (current g)
#define LW2     10240                   // 15 chunks
#define LW3     17920                   // 15 chunks
#define LHB     25600                   // 4 waves x ROWS_W x SH
#define LDS_SH  38912                   // 77824 B -> 2 blocks/CU

typedef __attribute__((ext_vector_type(8))) short short8;
typedef __attribute__((ext_vector_type(4))) float floatx4;

static __device__ __forceinline__ unsigned short f2bf(float f) {
  union { float f; unsigned u; } v; v.f = f;
  unsigned r = v.u + 0x7fffu + ((v.u >> 16) & 1u);   // RNE
  return (unsigned short)(r >> 16);
}

// ---- prologue: f32 weights -> bf16, swizzled to MFMA B-fragment lane order ----
// chunk: ws[chunk*512 + lane*8 + j] = W[n = ct*16 + (lane&15)][k = ks*32 + (lane>>4)*8 + j]
__global__ void convert_weights(const float* __restrict__ W1, const float* __restrict__ W2,
                                const float* __restrict__ W3, const float* __restrict__ W4,
                                unsigned short* __restrict__ ws) {
  int t = blockIdx.x * 256 + threadIdx.x;
  if (t >= WTOT) return;
  int chunk = t >> 9, r = t & 511;
  int lane = r >> 3, j = r & 7;
  int l16 = lane & 15, quad = lane >> 4;
  float val;
  if (chunk < 160) {                              // W1: [G][80][128]
    int g = chunk / 20, rem = chunk % 20, ks = rem / 5, ct = rem % 5;
    int n = ct * 16 + l16, k = ks * 32 + quad * 8 + j;
    val = W1[(g * FDIM + n) * DDIM + k];
  } else if (chunk < 175) {                       // W2: [80][80] -> k padded 96
    int c = chunk - 160, ks = c / 5, ct = c % 5;
    int n = ct * 16 + l16, k = ks * 32 + quad * 8 + j;
    val = (k < FDIM) ? W2[n * FDIM + k] : 0.f;
  } else if (chunk < 190) {                       // W3
    int c = chunk - 175, ks = c / 5, ct = c % 5;
    int n = ct * 16 + l16, k = ks * 32 + quad * 8 + j;
    val = (k < FDIM) ? W3[n * FDIM + k] : 0.f;
  } else {                                        // W4: [G][18][80] -> [G][32][96]
    int c = chunk - 190, g = c / 6, rem = c % 6, ks = rem >> 1, ct = rem & 1;
    int n = ct * 16 + l16, k = ks * 32 + quad * 8 + j;
    val = (n < ADIM && k < FDIM) ? W4[(g * ADIM + n) * FDIM + k] : 0.f;
  }
  ws[t] = f2bf(val);
}

// ---- per-g staging: W1[g] -> LDS (barrier-pair), W4/b1/b4 -> registers ----
static __device__ __forceinline__ void stage_game(
    int g, const unsigned short* __restrict__ wsw, unsigned short* smem,
    const float* __restrict__ b1, const float* __restrict__ b4,
    int tid, int lane, int l16,
    short8 w4f[6], float b1v[5], float b4v[2])
{
  __syncthreads();                                // all waves done with old W1
  {
    const short8* src = (const short8*)(wsw + W1SW + g * (20 * 512));
    short8* dst = (short8*)(smem + LW1);
#pragma unroll
    for (int i = 0; i < 5; ++i)
      dst[i * 256 + tid] = src[i * 256 + tid];
  }
  __syncthreads();                                // new W1 visible
#pragma unroll
  for (int ks = 0; ks < 3; ++ks)
#pragma unroll
    for (int ct = 0; ct < 2; ++ct)
      w4f[ks * 2 + ct] = *(const short8*)(wsw + W4SW + (((g * 3 + ks) * 2) + ct) * 512 + lane * 8);
#pragma unroll
  for (int ct = 0; ct < 5; ++ct) b1v[ct] = b1[g * FDIM + ct * 16 + l16];
#pragma unroll
  for (int ct = 0; ct < 2; ++ct) {
    int col = ct * 16 + l16;
    b4v[ct] = (col < ADIM) ? b4[g * ADIM + col] : 0.f;
  }
}

// Shared 80x80 layer on wave-private hbuf (32 rows), in place; W from LDS, bias in regs.
static __device__ __forceinline__ void mlp_layer_inplace(
    unsigned short* hbuf, const unsigned short* lw, const float bv[5],
    int lane, int l16, int quad)
{
  short8 a[2][3];
#pragma unroll
  for (int s = 0; s < 2; ++s)
#pragma unroll
    for (int ks = 0; ks < 3; ++ks)
      a[s][ks] = *(const short8*)(hbuf + (s * 16 + l16) * SH + ks * 32 + quad * 8);

  floatx4 acc[2][5];
#pragma unroll
  for (int s = 0; s < 2; ++s)
#pragma unroll
    for (int ct = 0; ct < 5; ++ct) acc[s][ct] = (floatx4){0.f, 0.f, 0.f, 0.f};
#pragma unroll
  for (int ks = 0; ks < 3; ++ks)
#pragma unroll
    for (int ct = 0; ct < 5; ++ct) {
      short8 bf = *(const short8*)(lw + (ks * 5 + ct) * 512 + lane * 8);
      acc[0][ct] = __builtin_amdgcn_mfma_f32_16x16x32_bf16(a[0][ks], bf, acc[0][ct], 0, 0, 0);
      acc[1][ct] = __builtin_amdgcn_mfma_f32_16x16x32_bf16(a[1][ks], bf, acc[1][ct], 0, 0, 0);
    }
#pragma unroll
  for (int s = 0; s < 2; ++s)
#pragma unroll
    for (int ct = 0; ct < 5; ++ct) {
      int col = ct * 16 + l16;
#pragma unroll
      for (int r = 0; r < 4; ++r) {
        int row = s * 16 + quad * 4 + r;          // C/D: col=lane&15, row=quad*4+reg
        hbuf[row * SH + col] = f2bf(fmaxf(acc[s][ct][r] + bv[ct], 0.f));
      }
    }
}

// Full 4-layer tile compute for one game g. MASKED: store h1/out only where idx==g.
template<bool MASKED>
static __device__ __forceinline__ void compute_tile(
    unsigned short* smem, unsigned short* hbuf,
    const short8 afrag[2][4], const short8 w4f[6],
    const float b1v[5], const float b2v[5], const float b3v[5], const float b4v[2],
    const int idxr[2][4], int g, size_t row0,
    int lane, int l16, int quad, float* __restrict__ out)
{
  // ---- layer 1 (W1 from LDS) ----
  {
    floatx4 acc[2][5];
#pragma unroll
    for (int s = 0; s < 2; ++s)
#pragma unroll
      for (int ct = 0; ct < 5; ++ct) acc[s][ct] = (floatx4){0.f, 0.f, 0.f, 0.f};
#pragma unroll
    for (int ks = 0; ks < 4; ++ks)
#pragma unroll
      for (int ct = 0; ct < 5; ++ct) {
        short8 bf = *(const short8*)(smem + LW1 + (ks * 5 + ct) * 512 + lane * 8);
        acc[0][ct] = __builtin_amdgcn_mfma_f32_16x16x32_bf16(afrag[0][ks], bf, acc[0][ct], 0, 0, 0);
        acc[1][ct] = __builtin_amdgcn_mfma_f32_16x16x32_bf16(afrag[1][ks], bf, acc[1][ct], 0, 0, 0);
      }
#pragma unroll
    for (int s = 0; s < 2; ++s)
#pragma unroll
      for (int ct = 0; ct < 5; ++ct) {
        int col = ct * 16 + l16;
#pragma unroll
        for (int r = 0; r < 4; ++r) {
          if (!MASKED || idxr[s][r] == g) {
            int row = s * 16 + quad * 4 + r;
            hbuf[row * SH + col] = f2bf(fmaxf(acc[s][ct][r] + b1v[ct], 0.f));
          }
        }
      }
  }
  // ---- layers 2,3 ----
  mlp_layer_inplace(hbuf, smem + LW2, b2v, lane, l16, quad);
  mlp_layer_inplace(hbuf, smem + LW3, b3v, lane, l16, quad);
  // ---- layer 4 (W4 in regs) ----
  {
    short8 a3[2][3];
#pragma unroll
    for (int s = 0; s < 2; ++s)
#pragma unroll
      for (int ks = 0; ks < 3; ++ks)
        a3[s][ks] = *(const short8*)(hbuf + (s * 16 + l16) * SH + ks * 32 + quad * 8);
    floatx4 acc[2][2];
#pragma unroll
    for (int s = 0; s < 2; ++s)
#pragma unroll
      for (int ct = 0; ct < 2; ++ct) acc[s][ct] = (floatx4){0.f, 0.f, 0.f, 0.f};
#pragma unroll
    for (int ks = 0; ks < 3; ++ks)
#pragma unroll
      for (int ct = 0; ct < 2; ++ct) {
        acc[0][ct] = __builtin_amdgcn_mfma_f32_16x16x32_bf16(a3[0][ks], w4f[ks * 2 + ct], acc[0][ct], 0, 0, 0);
        acc[1][ct] = __builtin_amdgcn_mfma_f32_16x16x32_bf16(a3[1][ks], w4f[ks * 2 + ct], acc[1][ct], 0, 0, 0);
      }
#pragma unroll
    for (int s = 0; s < 2; ++s)
#pragma unroll
      for (int ct = 0; ct < 2; ++ct) {
        int col = ct * 16 + l16;
        if (col < ADIM) {
#pragma unroll
          for (int r = 0; r < 4; ++r) {
            if (!MASKED || idxr[s][r] == g)
              out[(row0 + s * 16 + quad * 4 + r) * ADIM + col] = acc[s][ct][r] + b4v[ct];
          }
        }
      }
  }
}

__global__ __launch_bounds__(256, 2) void gym_fused(
    const float* __restrict__ state, const int* __restrict__ idx,
    const unsigned short* __restrict__ wsw,
    const float* __restrict__ b1, const float* __restrict__ b2,
    const float* __restrict__ b3, const float* __restrict__ b4,
    float* __restrict__ out)
{
  __shared__ __align__(16) unsigned short smem[LDS_SH];

  const int tid  = threadIdx.x;
  const int lane = tid & 63;
  const int wv   = tid >> 6;
  const int l16  = lane & 15;
  const int quad = lane >> 4;
  unsigned short* hbuf = smem + LHB + wv * (ROWS_W * SH);
  const size_t blk0 = (size_t)blockIdx.x * SPAN;
  const short8 zero8 = {0, 0, 0, 0, 0, 0, 0, 0};

  // ---- stage W2+W3 (1920 short8, contiguous in wsw) ----
  {
    const short8* src = (const short8*)(wsw + W2SW);
    short8* dst = (short8*)(smem + LW2);
#pragma unroll
    for (int i = 0; i < 8; ++i) {
      int t = i * 256 + tid;
      if (t < 1920) dst[t] = src[t];
    }
  }
  // ---- zero hbuf pad cols 80..95 (uninit LDS; NaN*0=NaN through MFMA) ----
  {
    int r = lane >> 1, cc = lane & 1;
    *(short8*)(hbuf + r * SH + 80 + cc * 8) = zero8;
  }
  // ---- loop-invariant biases ----
  float b2v[5], b3v[5];
#pragma unroll
  for (int ct = 0; ct < 5; ++ct) {
    b2v[ct] = b2[ct * 16 + l16];
    b3v[ct] = b3[ct * 16 + l16];
  }
  // ---- initial game staging (includes the block-start barrier) ----
  int curr_g = idx[blk0];
  short8 w4f[6]; float b1v[5], b4v[2];
  stage_game(curr_g, wsw, smem, b1, b4, tid, lane, l16, w4f, b1v, b4v);

  // ---- first tile's state fragments ----
  short8 afrag[2][4];
#pragma unroll
  for (int s = 0; s < 2; ++s) {
    const float* sp = state + (blk0 + wv * ROWS_W + s * 16 + l16) * DDIM + quad * 8;
#pragma unroll
    for (int ks = 0; ks < 4; ++ks) {
      floatx4 va = *(const floatx4*)(sp + ks * 32);
      floatx4 vb = *(const floatx4*)(sp + ks * 32 + 4);
      short8 f;
      f[0] = (short)f2bf(va[0]); f[1] = (short)f2bf(va[1]);
      f[2] = (short)f2bf(va[2]); f[3] = (short)f2bf(va[3]);
      f[4] = (short)f2bf(vb[0]); f[5] = (short)f2bf(vb[1]);
      f[6] = (short)f2bf(vb[2]); f[7] = (short)f2bf(vb[3]);
      afrag[s][ks] = f;
    }
  }
  int tg_lo = idx[blk0];
  int tg_hi = idx[blk0 + MT - 1];

  for (int it = 0; it < NITER; ++it) {
    const size_t trow0 = blk0 + (size_t)it * MT;
    const size_t row0  = trow0 + wv * ROWS_W;

    // ---- prefetch next tile: raw state + g-range (latency hidden by this tile) ----
    floatx4 fnext[16];
    int ntg_lo = 0, ntg_hi = 0;
    if (it + 1 < NITER) {
      ntg_lo = idx[trow0 + MT];
      ntg_hi = idx[trow0 + 2 * MT - 1];
#pragma unroll
      for (int s = 0; s < 2; ++s) {
        const float* sp = state + (row0 + MT + s * 16 + l16) * DDIM + quad * 8;
#pragma unroll
        for (int ks = 0; ks < 4; ++ks) {
          fnext[(s * 4 + ks) * 2]     = *(const floatx4*)(sp + ks * 32);
          fnext[(s * 4 + ks) * 2 + 1] = *(const floatx4*)(sp + ks * 32 + 4);
        }
      }
    }

    // ---- compute current tile ----
    if (tg_lo == tg_hi) {                          // uniform tile (the common case)
      if (tg_lo != curr_g) {
        stage_game(tg_lo, wsw, smem, b1, b4, tid, lane, l16, w4f, b1v, b4v);
        curr_g = tg_lo;
      }
      int dummy[2][4];
      compute_tile<false>(smem, hbuf, afrag, w4f, b1v, b2v, b3v, b4v,
                          dummy, curr_g, row0, lane, l16, quad, out);
    } else {                                       // boundary tile (rare)
      int idxr[2][4];
#pragma unroll
      for (int s = 0; s < 2; ++s)
#pragma unroll
        for (int r = 0; r < 4; ++r) idxr[s][r] = idx[row0 + s * 16 + quad * 4 + r];
      for (int g = tg_lo; g <= tg_hi; ++g) {
        if (g != curr_g) {
          stage_game(g, wsw, smem, b1, b4, tid, lane, l16, w4f, b1v, b4v);
          curr_g = g;
        }
        compute_tile<true>(smem, hbuf, afrag, w4f, b1v, b2v, b3v, b4v,
                           idxr, g, row0, lane, l16, quad, out);
      }
    }

    // ---- convert prefetched state for next iter ----
    if (it + 1 < NITER) {
#pragma unroll
      for (int s = 0; s < 2; ++s)
#pragma unroll
        for (int ks = 0; ks < 4; ++ks) {
          floatx4 va = fnext[(s * 4 + ks) * 2];
          floatx4 vb = fnext[(s * 4 + ks) * 2 + 1];
          short8 f;
          f[0] = (short)f2bf(va[0]); f[1] = (short)f2bf(va[1]);
          f[2] = (short)f2bf(va[2]); f[3] = (short)f2bf(va[3]);
          f[4] = (short)f2bf(vb[0]); f[5] = (short)f2bf(vb[1]);
          f[6] = (short)f2bf(vb[2]); f[7] = (short)f2bf(vb[3]);
          afrag[s][ks] = f;
        }
      tg_lo = ntg_lo;
      tg_hi = ntg_hi;
    }
  }
}

extern "C" void kernel_launch(void* const* d_in, const int* in_sizes, int n_in,
                              void* d_out, int out_size, void* d_ws, size_t ws_size,
                              hipStream_t stream) {
  const float* state = (const float*)d_in[0];
  const int*   idx   = (const int*)d_in[1];
  const float* W1    = (const float*)d_in[2];
  const float* b1    = (const float*)d_in[3];
  const float* W2    = (const float*)d_in[4];
  const float* b2    = (const float*)d_in[5];
  const float* W3    = (const float*)d_in[6];
  const float* b3    = (const float*)d_in[7];
  const float* W4    = (const float*)d_in[8];
  const float* b4    = (const float*)d_in[9];
  float*       out   = (float*)d_out;
  unsigned short* wsw = (unsigned short*)d_ws;   // 243712 B used

  convert_weights<<<(WTOT + 255) / 256, 256, 0, stream>>>(W1, W2, W3, W4, wsw);
  gym_fused<<<B_TOT / SPAN, 256, 0, stream>>>(state, idx, wsw, b1, b2, b3, b4, out);
}

// Round 9
// 249.259 us; speedup vs baseline: 1.0212x; 1.0212x over previous
//
#include <hip/hip_runtime.h>

// GymNetwork: routed MLP, B=262144, D=128 -> F=80 -> 80 -> 80 -> A=18, G=8 (idx sorted).
// f32 I/O, bf16 MFMA compute (threshold 6e-2 = 8*bf16_eps*max|ref|).
//
// R3-R8 lesson: the bottleneck was never occupancy/barriers/BW -- it's the per-wave
// serial chain of ~10 memory hops with only a few loads in flight (VGPR-limited).
// R9: ALL weights pinned in registers (W1[g] 80 + W2 60 + W3 60 + W4 24 = 224 VGPRs of
// bf16 B-fragments, preloaded from the swizzled d_ws chunks). 1 wave/SIMD
// (__launch_bounds__(256,1), 512-VGPR budget), 256 blocks x 4 waves = 1024 waves,
// each streams 16 tiles of 16 rows (contiguous 256-row span) with 1-tile-ahead state
// prefetch. Steady chain: prefetched state -> reg MFMAs -> wave-private LDS h -> out.
// Routing: per-tile [tg_lo,tg_hi] from idx (sorted); unified mask path (idx[row]==g).

#define B_TOT   262144
#define DDIM    128
#define FDIM    80
#define ADIM    18
#define TILE    16     // rows per tile
#define NT      16     // tiles per wave
#define SPAN_W  (TILE*NT)   // 256 rows per wave
#define SH      104    // LDS stride (shorts) for h rows (16B-aligned, 2-way-free banks)

// swizzled bf16 weight workspace in d_ws (shorts); 512-short (1KB) chunks, lane-major
#define W1SW    0                       // 160 chunks: ((g*4+ks)*5+ct)
#define W2SW    81920                   // 15 chunks: (ks*5+ct), k pads zeroed
#define W3SW    89600                   // 15 chunks
#define W4SW    97280                   // 48 chunks: ((g*3+ks)*2+ct), n/k pads zeroed
#define WTOT    121856                  // shorts = 243712 bytes

typedef __attribute__((ext_vector_type(8))) short short8;
typedef __attribute__((ext_vector_type(4))) float floatx4;
typedef __attribute__((ext_vector_type(4))) int int4v;

static __device__ __forceinline__ unsigned short f2bf(float f) {
  union { float f; unsigned u; } v; v.f = f;
  unsigned r = v.u + 0x7fffu + ((v.u >> 16) & 1u);   // RNE
  return (unsigned short)(r >> 16);
}

// ---- prologue: f32 weights -> bf16, swizzled to MFMA B-fragment lane order ----
// chunk: ws[chunk*512 + lane*8 + j] = W[n = ct*16 + (lane&15)][k = ks*32 + (lane>>4)*8 + j]
__global__ void convert_weights(const float* __restrict__ W1, const float* __restrict__ W2,
                                const float* __restrict__ W3, const float* __restrict__ W4,
                                unsigned short* __restrict__ ws) {
  int t = blockIdx.x * 256 + threadIdx.x;
  if (t >= WTOT) return;
  int chunk = t >> 9, r = t & 511;
  int lane = r >> 3, j = r & 7;
  int l16 = lane & 15, quad = lane >> 4;
  float val;
  if (chunk < 160) {                              // W1: [G][80][128]
    int g = chunk / 20, rem = chunk % 20, ks = rem / 5, ct = rem % 5;
    int n = ct * 16 + l16, k = ks * 32 + quad * 8 + j;
    val = W1[(g * FDIM + n) * DDIM + k];
  } else if (chunk < 175) {                       // W2: [80][80] -> k padded 96
    int c = chunk - 160, ks = c / 5, ct = c % 5;
    int n = ct * 16 + l16, k = ks * 32 + quad * 8 + j;
    val = (k < FDIM) ? W2[n * FDIM + k] : 0.f;
  } else if (chunk < 190) {                       // W3
    int c = chunk - 175, ks = c / 5, ct = c % 5;
    int n = ct * 16 + l16, k = ks * 32 + quad * 8 + j;
    val = (k < FDIM) ? W3[n * FDIM + k] : 0.f;
  } else {                                        // W4: [G][18][80] -> [G][32][96]
    int c = chunk - 190, g = c / 6, rem = c % 6, ks = rem >> 1, ct = rem & 1;
    int n = ct * 16 + l16, k = ks * 32 + quad * 8 + j;
    val = (n < ADIM && k < FDIM) ? W4[(g * ADIM + n) * FDIM + k] : 0.f;
  }
  ws[t] = f2bf(val);
}

__global__ __launch_bounds__(256, 1) void gym_fused(
    const float* __restrict__ state, const int* __restrict__ idx,
    const unsigned short* __restrict__ wsw,
    const float* __restrict__ b1, const float* __restrict__ b2,
    const float* __restrict__ b3, const float* __restrict__ b4,
    float* __restrict__ out)
{
  __shared__ __align__(16) unsigned short s_h[4][TILE * SH];  // 13312 B, wave-private

  const int tid  = threadIdx.x;
  const int lane = tid & 63;
  const int wv   = tid >> 6;
  const int l16  = lane & 15;
  const int quad = lane >> 4;
  unsigned short* hbuf = s_h[wv];
  const size_t row0w = ((size_t)blockIdx.x * 4 + wv) * SPAN_W;  // this wave's 256 rows
  const short8 zero8 = {0, 0, 0, 0, 0, 0, 0, 0};

  // ---- zero hbuf k-pad cols 80..95 once (uninit LDS; NaN*0=NaN through MFMA) ----
  if (lane < 32) {
    int r = lane >> 1, cc = lane & 1;
    *(short8*)(hbuf + r * SH + 80 + cc * 8) = zero8;
  }

  // ---- pin shared weights + biases in registers (swizzled chunks: 1 dwordx4/lane) ----
  short8 w2f[15], w3f[15];
#pragma unroll
  for (int i = 0; i < 15; ++i) w2f[i] = *(const short8*)(wsw + W2SW + i * 512 + lane * 8);
#pragma unroll
  for (int i = 0; i < 15; ++i) w3f[i] = *(const short8*)(wsw + W3SW + i * 512 + lane * 8);
  float b2v[5], b3v[5];
#pragma unroll
  for (int ct = 0; ct < 5; ++ct) {
    b2v[ct] = b2[ct * 16 + l16];
    b3v[ct] = b3[ct * 16 + l16];
  }

  // ---- per-game registers: W1[g] (20 frags), W4[g] (6 frags), b1/b4 ----
  short8 w1f[20], w4f[6];
  float b1v[5], b4v[2];
  int curr_g = idx[row0w];
#define STAGE_GAME(G)                                                              \
  do {                                                                             \
    _Pragma("unroll")                                                              \
    for (int i = 0; i < 20; ++i)                                                   \
      w1f[i] = *(const short8*)(wsw + W1SW + ((G) * 20 + i) * 512 + lane * 8);     \
    _Pragma("unroll")                                                              \
    for (int i = 0; i < 6; ++i)                                                    \
      w4f[i] = *(const short8*)(wsw + W4SW + ((G) * 6 + i) * 512 + lane * 8);      \
    _Pragma("unroll")                                                              \
    for (int ct = 0; ct < 5; ++ct) b1v[ct] = b1[(G) * FDIM + ct * 16 + l16];       \
    _Pragma("unroll")                                                              \
    for (int ct = 0; ct < 2; ++ct) {                                               \
      int col = ct * 16 + l16;                                                     \
      b4v[ct] = (col < ADIM) ? b4[(G) * ADIM + col] : 0.f;                         \
    }                                                                              \
  } while (0)
  STAGE_GAME(curr_g);

  // ---- prefetch tile 0: raw state (8 dwordx4) + idx (1 int4) ----
  floatx4 praw[8];
  int4v pidx;
  {
    const float* sp = state + (row0w + l16) * DDIM + quad * 8;
#pragma unroll
    for (int ks = 0; ks < 4; ++ks) {
      praw[ks * 2]     = *(const floatx4*)(sp + ks * 32);
      praw[ks * 2 + 1] = *(const floatx4*)(sp + ks * 32 + 4);
    }
    pidx = *(const int4v*)(idx + row0w + quad * 4);
  }

  for (int t = 0; t < NT; ++t) {
    const size_t trow = row0w + (size_t)t * TILE;

    // ---- convert this tile's state to A-fragments ----
    short8 afrag[4];
#pragma unroll
    for (int ks = 0; ks < 4; ++ks) {
      floatx4 va = praw[ks * 2], vb = praw[ks * 2 + 1];
      short8 f;
      f[0] = (short)f2bf(va[0]); f[1] = (short)f2bf(va[1]);
      f[2] = (short)f2bf(va[2]); f[3] = (short)f2bf(va[3]);
      f[4] = (short)f2bf(vb[0]); f[5] = (short)f2bf(vb[1]);
      f[6] = (short)f2bf(vb[2]); f[7] = (short)f2bf(vb[3]);
      afrag[ks] = f;
    }
    int4v cidx = pidx;
    const int tg_lo = __shfl(cidx[0], 0);         // idx[trow]      (sorted)
    const int tg_hi = __shfl(cidx[3], 48);        // idx[trow + 15]

    // ---- issue prefetch for tile t+1 (hidden under this tile's compute) ----
    {
      const size_t nrow = (t + 1 < NT) ? trow + TILE : row0w;   // harmless reload at end
      const float* sp = state + (nrow + l16) * DDIM + quad * 8;
#pragma unroll
      for (int ks = 0; ks < 4; ++ks) {
        praw[ks * 2]     = *(const floatx4*)(sp + ks * 32);
        praw[ks * 2 + 1] = *(const floatx4*)(sp + ks * 32 + 4);
      }
      pidx = *(const int4v*)(idx + nrow + quad * 4);
    }

    // ---- compute: loop games in tile (1 iteration for uniform tiles) ----
    for (int g = tg_lo; g <= tg_hi; ++g) {
      if (g != curr_g) { STAGE_GAME(g); curr_g = g; }

      // layer 1: h1 = relu(state @ W1[g]^T + b1[g]); store rows where idx==g
      {
        floatx4 acc[5];
#pragma unroll
        for (int ct = 0; ct < 5; ++ct) acc[ct] = (floatx4){0.f, 0.f, 0.f, 0.f};
#pragma unroll
        for (int ks = 0; ks < 4; ++ks)
#pragma unroll
          for (int ct = 0; ct < 5; ++ct)
            acc[ct] = __builtin_amdgcn_mfma_f32_16x16x32_bf16(afrag[ks], w1f[ks * 5 + ct], acc[ct], 0, 0, 0);
#pragma unroll
        for (int ct = 0; ct < 5; ++ct) {
          int col = ct * 16 + l16;
#pragma unroll
          for (int r = 0; r < 4; ++r) {
            if (cidx[r] == g) {                    // row quad*4+r belongs to g
              int row = quad * 4 + r;
              hbuf[row * SH + col] = f2bf(fmaxf(acc[ct][r] + b1v[ct], 0.f));
            }
          }
        }
      }
      // layers 2,3: in-place on hbuf (read A-frags first; wave-private => program order)
#pragma unroll
      for (int L = 0; L < 2; ++L) {
        short8 a[3];
#pragma unroll
        for (int ks = 0; ks < 3; ++ks)
          a[ks] = *(const short8*)(hbuf + l16 * SH + ks * 32 + quad * 8);
        floatx4 acc[5];
#pragma unroll
        for (int ct = 0; ct < 5; ++ct) acc[ct] = (floatx4){0.f, 0.f, 0.f, 0.f};
#pragma unroll
        for (int ks = 0; ks < 3; ++ks)
#pragma unroll
          for (int ct = 0; ct < 5; ++ct) {
            short8 bf = (L == 0) ? w2f[ks * 5 + ct] : w3f[ks * 5 + ct];
            acc[ct] = __builtin_amdgcn_mfma_f32_16x16x32_bf16(a[ks], bf, acc[ct], 0, 0, 0);
          }
#pragma unroll
        for (int ct = 0; ct < 5; ++ct) {
          int col = ct * 16 + l16;
          float bv = (L == 0) ? b2v[ct] : b3v[ct];
#pragma unroll
          for (int r = 0; r < 4; ++r) {
            int row = quad * 4 + r;
            hbuf[row * SH + col] = f2bf(fmaxf(acc[ct][r] + bv, 0.f));
          }
        }
      }
      // layer 4: q = h3 @ W4[g]^T + b4[g]; masked f32 store
      {
        short8 a3[3];
#pragma unroll
        for (int ks = 0; ks < 3; ++ks)
          a3[ks] = *(const short8*)(hbuf + l16 * SH + ks * 32 + quad * 8);
        floatx4 acc[2];
#pragma unroll
        for (int ct = 0; ct < 2; ++ct) acc[ct] = (floatx4){0.f, 0.f, 0.f, 0.f};
#pragma unroll
        for (int ks = 0; ks < 3; ++ks)
#pragma unroll
          for (int ct = 0; ct < 2; ++ct)
            acc[ct] = __builtin_amdgcn_mfma_f32_16x16x32_bf16(a3[ks], w4f[ks * 2 + ct], acc[ct], 0, 0, 0);
#pragma unroll
        for (int ct = 0; ct < 2; ++ct) {
          int col = ct * 16 + l16;
          if (col < ADIM) {
#pragma unroll
            for (int r = 0; r < 4; ++r) {
              if (cidx[r] == g)
                out[(trow + quad * 4 + r) * ADIM + col] = acc[ct][r] + b4v[ct];
            }
          }
        }
      }
    }
  }
#undef STAGE_GAME
}

extern "C" void kernel_launch(void* const* d_in, const int* in_sizes, int n_in,
                              void* d_out, int out_size, void* d_ws, size_t ws_size,
                              hipStream_t stream) {
  const float* state = (const float*)d_in[0];
  const int*   idx   = (const int*)d_in[1];
  const float* W1    = (const float*)d_in[2];
  const float* b1    = (const float*)d_in[3];
  const float* W2    = (const float*)d_in[4];
  const float* b2    = (const float*)d_in[5];
  const float* W3    = (const float*)d_in[6];
  const float* b3    = (const float*)d_in[7];
  const float* W4    = (const float*)d_in[8];
  const float* b4    = (const float*)d_in[9];
  float*       out   = (float*)d_out;
  unsigned short* wsw = (unsigned short*)d_ws;   // 243712 B used

  convert_weights<<<(WTOT + 255) / 256, 256, 0, stream>>>(W1, W2, W3, W4, wsw);
  // 256 blocks x 4 waves = 1024 waves = 1 wave/SIMD chip-wide; each wave owns 256 rows
  gym_fused<<<B_TOT / (4 * SPAN_W), 256, 0, stream>>>(state, idx, wsw, b1, b2, b3, b4, out);
}

// Round 10
// 217.924 us; speedup vs baseline: 1.1680x; 1.1438x over previous
//
#include <hip/hip_runtime.h>

// GymNetwork: routed MLP, B=262144, D=128 -> F=80 -> 80 -> 80 -> A=18, G=8 (idx sorted).
// f32 I/O, bf16 MFMA compute (threshold 6e-2 = 8*bf16_eps*max|ref|).
//
// R10: (1) OPERAND SWAP: D^T = mfma(A=W, B=h) -> lane holds 4 consecutive n at fixed
// batch-row l16: h writes become ds_write_b64 (4x fewer), out stores packed float2,
// route mask = one bool/lane. (2) BIAS-IN-K: W2/W3/W4 chunks carry bias at k=80, h pad
// col80=1.0 -> no bias regs/adds for L2/L3/L4. (3) 4 waves/SIMD: weights in LDS
// (77824 B, 2 blocks/CU), 512-thread blocks, grid 512 (single co-resident generation),
// each wave streams 4 x 16-row tiles; W1[g] re-staged only on game change (rare).

#define B_TOT   262144
#define DDIM    128
#define FDIM    80
#define ADIM    18
#define SH      104    // LDS stride (shorts) for h rows
#define THREADS 512
#define SLAB    128    // rows per block-iteration (8 waves x 16)
#define NSLAB   4      // block rows = 512
#define GRID    (B_TOT / (SLAB * NSLAB))   // 512 blocks = 2/CU

// swizzled bf16 weight workspace in d_ws (shorts); 512-short (1KB) chunks, lane-major
#define W1SW    0                       // 160 chunks: ((g*4+ks)*5+ct)
#define W2SW    81920                   // 15 chunks: (ks*5+ct); k=80 holds b2, 81..95 zero
#define W3SW    89600                   // 15 chunks; k=80 holds b3
#define W4SW    97280                   // 48 chunks: (g*6+ks*2+ct); k=80 holds b4, n pads zero
#define WTOT    121856                  // shorts = 243712 bytes

// LDS layout (shorts)
#define LW1     0                       // 20 chunks (current g) = 10240
#define LW2     10240                   // 15 chunks = 7680
#define LW3     17920                   // 15 chunks = 7680
#define LHB     25600                   // 8 waves x 16 x SH = 13312
#define LDS_SH  38912                   // 77824 B -> 2 blocks/CU

typedef __attribute__((ext_vector_type(8))) short short8;
typedef __attribute__((ext_vector_type(4))) short short4v;
typedef __attribute__((ext_vector_type(2))) unsigned int uint2v;
typedef __attribute__((ext_vector_type(4))) float floatx4;
typedef __attribute__((ext_vector_type(2))) float floatx2;

static __device__ __forceinline__ unsigned short f2bf(float f) {
  union { float f; unsigned u; } v; v.f = f;
  unsigned r = v.u + 0x7fffu + ((v.u >> 16) & 1u);   // RNE
  return (unsigned short)(r >> 16);
}
// pack two f32 -> bf16x2 (lo | hi<<16), RNE
static __device__ __forceinline__ unsigned pk2(float a, float b) {
  union { float f; unsigned u; } x, y; x.f = a; y.f = b;
  unsigned ra = x.u + 0x7fffu + ((x.u >> 16) & 1u);
  unsigned rb = y.u + 0x7fffu + ((y.u >> 16) & 1u);
  return (ra >> 16) | (rb & 0xffff0000u);
}

// ---- prologue: f32 weights -> bf16 swizzled chunks; bias folded into k=80 column ----
// chunk: ws[chunk*512 + lane*8 + j] = W[n = ct*16 + (lane&15)][k = ks*32 + (lane>>4)*8 + j]
__global__ void convert_weights(const float* __restrict__ W1, const float* __restrict__ W2,
                                const float* __restrict__ W3, const float* __restrict__ W4,
                                const float* __restrict__ b2, const float* __restrict__ b3,
                                const float* __restrict__ b4, unsigned short* __restrict__ ws) {
  int t = blockIdx.x * 256 + threadIdx.x;
  if (t >= WTOT) return;
  int chunk = t >> 9, r = t & 511;
  int lane = r >> 3, j = r & 7;
  int l16 = lane & 15, quad = lane >> 4;
  float val;
  if (chunk < 160) {                              // W1: [G][80][128], no pads
    int g = chunk / 20, rem = chunk % 20, ks = rem / 5, ct = rem % 5;
    int n = ct * 16 + l16, k = ks * 32 + quad * 8 + j;
    val = W1[(g * FDIM + n) * DDIM + k];
  } else if (chunk < 175) {                       // W2: 80x80 -> 80x96, k80 = b2[n]
    int c = chunk - 160, ks = c / 5, ct = c % 5;
    int n = ct * 16 + l16, k = ks * 32 + quad * 8 + j;
    val = (k < FDIM) ? W2[n * FDIM + k] : (k == FDIM ? b2[n] : 0.f);
  } else if (chunk < 190) {                       // W3, k80 = b3[n]
    int c = chunk - 175, ks = c / 5, ct = c % 5;
    int n = ct * 16 + l16, k = ks * 32 + quad * 8 + j;
    val = (k < FDIM) ? W3[n * FDIM + k] : (k == FDIM ? b3[n] : 0.f);
  } else {                                        // W4: Gx18x80 -> Gx32x96, k80 = b4[g][n]
    int c = chunk - 190, g = c / 6, rem = c % 6, ks = rem >> 1, ct = rem & 1;
    int n = ct * 16 + l16, k = ks * 32 + quad * 8 + j;
    val = (n < ADIM) ? ((k < FDIM) ? W4[(g * ADIM + n) * FDIM + k]
                                   : (k == FDIM ? b4[g * ADIM + n] : 0.f)) : 0.f;
  }
  ws[t] = f2bf(val);
}

// W1[g] -> LDS (barrier pair; block-uniform call sites) + b1 fragment -> regs
static __device__ __forceinline__ void stage_game(
    int g, const unsigned short* __restrict__ wsw, unsigned short* smem,
    const float* __restrict__ b1, int tid, int quad, floatx4 b1v[5])
{
  __syncthreads();                                // all waves done with old W1
  const short8* src = (const short8*)(wsw + W1SW + g * (20 * 512));
  short8* dst = (short8*)(smem + LW1);
#pragma unroll
  for (int i = 0; i < 3; ++i) {
    int t = i * THREADS + tid;
    if (t < 1280) dst[t] = src[t];
  }
  __syncthreads();                                // new W1 visible
#pragma unroll
  for (int ct = 0; ct < 5; ++ct)                  // b1[n], n = ct*16 + quad*4 + r
    b1v[ct] = *(const floatx4*)(b1 + g * FDIM + ct * 16 + quad * 4);
}

__global__ __launch_bounds__(THREADS, 4) void gym_fused(
    const float* __restrict__ state, const int* __restrict__ idx,
    const unsigned short* __restrict__ wsw, const float* __restrict__ b1,
    float* __restrict__ out)
{
  __shared__ __align__(16) unsigned short smem[LDS_SH];

  const int tid  = threadIdx.x;
  const int lane = tid & 63;
  const int wv   = tid >> 6;
  const int l16  = lane & 15;
  const int quad = lane >> 4;
  unsigned short* hbuf = smem + LHB + wv * (16 * SH);
  const size_t blk0 = (size_t)blockIdx.x * (SLAB * NSLAB);

  // ---- stage W2+W3 (30 chunks = 1920 short8, contiguous in wsw) ----
  {
    const short8* src = (const short8*)(wsw + W2SW);
    short8* dst = (short8*)(smem + LW2);
#pragma unroll
    for (int i = 0; i < 4; ++i) {
      int t = i * THREADS + tid;
      if (t < 1920) dst[t] = src[t];
    }
  }
  // ---- hbuf pad cols 80..95: col80 = 1.0 (bias-in-k), 81..95 = 0 ----
  {
    int row = lane >> 2, grp = lane & 3;          // 16 rows x 4 groups of 4 shorts
    short4v v = {0, 0, 0, 0};
    if (grp == 0) v[0] = (short)0x3F80;           // bf16 1.0 at col 80
    *(short4v*)(hbuf + row * SH + 80 + grp * 4) = v;
  }

  // ---- initial game (covered by stage_game's barrier pair) ----
  int curr_g = idx[blk0];
  floatx4 b1v[5];
  stage_game(curr_g, wsw, smem, b1, tid, quad, b1v);

  for (int it = 0; it < NSLAB; ++it) {
    const size_t slab0 = blk0 + (size_t)it * SLAB;
    const size_t trow  = slab0 + wv * 16;         // this wave's 16 rows
    const int tg_lo = idx[slab0];
    const int tg_hi = idx[slab0 + SLAB - 1];      // idx sorted
    const int midx  = idx[trow + l16];            // this lane's row's game

    // ---- state B'-fragments: row = l16, k = quad*8+j (f32 -> bf16 in regs) ----
    short8 afrag[4];
    {
      const float* sp = state + (trow + l16) * DDIM + quad * 8;
#pragma unroll
      for (int ks = 0; ks < 4; ++ks) {
        floatx4 va = *(const floatx4*)(sp + ks * 32);
        floatx4 vb = *(const floatx4*)(sp + ks * 32 + 4);
        short8 f;
        unsigned u0 = pk2(va[0], va[1]), u1 = pk2(va[2], va[3]);
        unsigned u2 = pk2(vb[0], vb[1]), u3 = pk2(vb[2], vb[3]);
        f[0] = (short)(u0 & 0xffff); f[1] = (short)(u0 >> 16);
        f[2] = (short)(u1 & 0xffff); f[3] = (short)(u1 >> 16);
        f[4] = (short)(u2 & 0xffff); f[5] = (short)(u2 >> 16);
        f[6] = (short)(u3 & 0xffff); f[7] = (short)(u3 >> 16);
        afrag[ks] = f;
      }
    }

    for (int g = tg_lo; g <= tg_hi; ++g) {        // block-uniform loop (slab range)
      if (g != curr_g) { stage_game(g, wsw, smem, b1, tid, quad, b1v); curr_g = g; }

      // ---- L1: D^T = mfma(W1, state); lane: row=l16, n=ct*16+quad*4+r ----
      {
        floatx4 acc[5];
#pragma unroll
        for (int ct = 0; ct < 5; ++ct) acc[ct] = (floatx4){0.f, 0.f, 0.f, 0.f};
#pragma unroll
        for (int ks = 0; ks < 4; ++ks)
#pragma unroll
          for (int ct = 0; ct < 5; ++ct) {
            short8 wf = *(const short8*)(smem + LW1 + (ks * 5 + ct) * 512 + lane * 8);
            acc[ct] = __builtin_amdgcn_mfma_f32_16x16x32_bf16(wf, afrag[ks], acc[ct], 0, 0, 0);
          }
#pragma unroll
        for (int ct = 0; ct < 5; ++ct) {
          floatx4 v = acc[ct] + b1v[ct];
          uint2v u;
          u[0] = pk2(fmaxf(v[0], 0.f), fmaxf(v[1], 0.f));
          u[1] = pk2(fmaxf(v[2], 0.f), fmaxf(v[3], 0.f));
          if (midx == g)                           // whole row belongs to this lane
            *(uint2v*)(hbuf + l16 * SH + ct * 16 + quad * 4) = u;
        }
      }
      // ---- L2, L3: in-place (read h frags to regs first; wave-private buffer) ----
#pragma unroll
      for (int L = 0; L < 2; ++L) {
        short8 hf[3];
#pragma unroll
        for (int ks = 0; ks < 3; ++ks)
          hf[ks] = *(const short8*)(hbuf + l16 * SH + ks * 32 + quad * 8);
        floatx4 acc[5];
#pragma unroll
        for (int ct = 0; ct < 5; ++ct) acc[ct] = (floatx4){0.f, 0.f, 0.f, 0.f};
        const int lw = (L == 0) ? LW2 : LW3;
#pragma unroll
        for (int ks = 0; ks < 3; ++ks)
#pragma unroll
          for (int ct = 0; ct < 5; ++ct) {
            short8 wf = *(const short8*)(smem + lw + (ks * 5 + ct) * 512 + lane * 8);
            acc[ct] = __builtin_amdgcn_mfma_f32_16x16x32_bf16(wf, hf[ks], acc[ct], 0, 0, 0);
          }
#pragma unroll
        for (int ct = 0; ct < 5; ++ct) {          // bias came via k=80; just relu+pack
          uint2v u;
          u[0] = pk2(fmaxf(acc[ct][0], 0.f), fmaxf(acc[ct][1], 0.f));
          u[1] = pk2(fmaxf(acc[ct][2], 0.f), fmaxf(acc[ct][3], 0.f));
          *(uint2v*)(hbuf + l16 * SH + ct * 16 + quad * 4) = u;
        }
      }
      // ---- L4: W4 frags from global (L2-hot); packed float2 out stores ----
      {
        short8 hf[3];
#pragma unroll
        for (int ks = 0; ks < 3; ++ks)
          hf[ks] = *(const short8*)(hbuf + l16 * SH + ks * 32 + quad * 8);
        floatx4 acc[2];
#pragma unroll
        for (int ct = 0; ct < 2; ++ct) acc[ct] = (floatx4){0.f, 0.f, 0.f, 0.f};
#pragma unroll
        for (int ks = 0; ks < 3; ++ks)
#pragma unroll
          for (int ct = 0; ct < 2; ++ct) {
            short8 wf = *(const short8*)(wsw + W4SW + (g * 6 + ks * 2 + ct) * 512 + lane * 8);
            acc[ct] = __builtin_amdgcn_mfma_f32_16x16x32_bf16(wf, hf[ks], acc[ct], 0, 0, 0);
          }
        if (midx == g) {
          float* op = out + (trow + l16) * ADIM;   // n = ct*16 + quad*4 + r, valid n<18
          *(floatx2*)(op + quad * 4)     = (floatx2){acc[0][0], acc[0][1]};
          *(floatx2*)(op + quad * 4 + 2) = (floatx2){acc[0][2], acc[0][3]};
          if (quad == 0)
            *(floatx2*)(op + 16) = (floatx2){acc[1][0], acc[1][1]};
        }
      }
    }
  }
}

extern "C" void kernel_launch(void* const* d_in, const int* in_sizes, int n_in,
                              void* d_out, int out_size, void* d_ws, size_t ws_size,
                              hipStream_t stream) {
  const float* state = (const float*)d_in[0];
  const int*   idx   = (const int*)d_in[1];
  const float* W1    = (const float*)d_in[2];
  const float* b1    = (const float*)d_in[3];
  const float* W2    = (const float*)d_in[4];
  const float* b2    = (const float*)d_in[5];
  const float* W3    = (const float*)d_in[6];
  const float* b3    = (const float*)d_in[7];
  const float* W4    = (const float*)d_in[8];
  const float* b4    = (const float*)d_in[9];
  float*       out   = (float*)d_out;
  unsigned short* wsw = (unsigned short*)d_ws;   // 243712 B used

  convert_weights<<<(WTOT + 255) / 256, 256, 0, stream>>>(W1, W2, W3, W4, b2, b3, b4, wsw);
  gym_fused<<<GRID, THREADS, 0, stream>>>(state, idx, wsw, b1, out);
}